// Round 6
// baseline (214.404 us; speedup 1.0000x reference)
//
#include <hip/hip_runtime.h>
#include <stdint.h>

#define M_DIM 8192
#define K_DIM 4096
#define N_DIM 4096

using i32x4 = __attribute__((ext_vector_type(4))) int;

typedef const __attribute__((address_space(1))) void g_void;
typedef __attribute__((address_space(3))) void lds_void;

__device__ __forceinline__ void gload_lds16(const void* g, void* l) {
  // async global->LDS, 16B/lane; LDS dest = wave-uniform base + lane*16
  __builtin_amdgcn_global_load_lds((g_void*)g, (lds_void*)l, 16, 0, 0);
}

__device__ __forceinline__ void barrier_raw() {
  asm volatile("" ::: "memory");
  __builtin_amdgcn_s_barrier();
  asm volatile("" ::: "memory");
}

__device__ __forceinline__ int sign4(float4 v) {
  int a = (v.x > 0.f) - (v.x < 0.f);
  int b = (v.y > 0.f) - (v.y < 0.f);
  int c = (v.z > 0.f) - (v.z < 0.f);
  int d = (v.w > 0.f) - (v.w < 0.f);
  return (a & 255) | ((b & 255) << 8) | ((c & 255) << 16) | ((d & 255) << 24);
}

// ---- pack x: fp32 [M][K] -> int8 sign [M][K] ----
__global__ void pack_x_kernel(const float* __restrict__ in,
                              int8_t* __restrict__ out, long n) {
  long i0 = ((long)blockIdx.x * blockDim.x + threadIdx.x) * 16;
  long stride = (long)gridDim.x * blockDim.x * 16;
  for (long i = i0; i < n; i += stride) {
    const float4* p = reinterpret_cast<const float4*>(in + i);
    i32x4 r;
    r.x = sign4(p[0]);
    r.y = sign4(p[1]);
    r.z = sign4(p[2]);
    r.w = sign4(p[3]);
    *reinterpret_cast<i32x4*>(out + i) = r;
  }
}

// ---- pack w: fp32 [K][N] -> int8 sign, TRANSPOSED to [N][K] ----
__global__ void pack_wt_kernel(const float* __restrict__ w,
                               int8_t* __restrict__ wt) {
  __shared__ int8_t tile[64 * 68];
  int n0 = blockIdx.x * 64;
  int k0 = blockIdx.y * 64;
  int t = threadIdx.x;
#pragma unroll
  for (int i = 0; i < 16; ++i) {
    int flat = t + 256 * i;
    int r = flat >> 6;          // k-local
    int c = flat & 63;          // n-local (coalesced)
    float v = w[(long)(k0 + r) * N_DIM + n0 + c];
    tile[c * 68 + r] = (int8_t)((v > 0.f) - (v < 0.f));
  }
  __syncthreads();
#pragma unroll
  for (int i = 0; i < 4; ++i) {
    int flat = t + 256 * i;
    int nn = flat >> 4;
    int kk = (flat & 15) << 2;
    int word = *reinterpret_cast<const int*>(&tile[nn * 68 + kk]);
    *reinterpret_cast<int*>(wt + (long)(n0 + nn) * K_DIM + k0 + kk) = word;
  }
}

// ---- i8 GEMM: 256x256 tile, BK=64, 8 waves (2Mx4N), mfma_i32_16x16x64_i8.
// A: LDS-staged (4-deep x 16KB = 64 KiB, global_load_lds, R2 zero-conflict
//    swizzle). B: DIRECT global->VGPR, 1-tile register prefetch (L2-resident
//    panel; drops LDS port demand from ~1540 to ~960 cyc/tile < MFMA 1306).
// vmcnt ledger (in-order, shared by B-regs and A-stage):
//   entering tile t: [B(t)x4, A(t+1)x2] outstanding.
//   issue B(t+1)x4, A(t+2)x2 -> 12; vmcnt(6) retires B(t)+A(t+1); barrier;
//   read 8 A-frags; lgkm(4) -> MFMA ph0; lgkm(0) -> MFMA ph1.
// Slot reuse: A(t+2) written into slot (t+2)&3, last read at tile t-2, all
// reads retired in-tile (lgkm(0) before ph1) and 2 barriers have passed.
template <int VM, bool ISSUE_B, bool ISSUE_A>
__device__ __forceinline__ void tile_step(
    int t, const int8_t* __restrict__ Asrc, const int8_t* __restrict__ Bsrc,
    long sOff0, long sOff1, long bOffG, int dstOff, int8_t* lds, int aRd,
    i32x4 (&bfC)[4], i32x4 (&bfN)[4], i32x4 (&acc)[8][4]) {
  const int8_t* buf = lds + (t & 3) * 16384;
  // step1: B(t+1) fragment prefetch (global -> VGPR)
  if (ISSUE_B) {
    long kb = bOffG + (long)(t + 1) * 64;
#pragma unroll
    for (int n = 0; n < 4; ++n)
      bfN[n] =
          *reinterpret_cast<const i32x4*>(Bsrc + kb + (long)n * 16 * K_DIM);
  }
  // step2: A(t+2) staging (global -> LDS)
  if (ISSUE_A) {
    long kn = (long)(t + 2) * 64;
    int8_t* nbuf = lds + ((t + 2) & 3) * 16384;
    gload_lds16(Asrc + sOff0 + kn, nbuf + dstOff);
    gload_lds16(Asrc + sOff1 + kn, nbuf + 8192 + dstOff);
  }
  // step3: counted vm-gate (retires B(t) regs + A(t+1) staging)
  if (VM == 6) asm volatile("s_waitcnt vmcnt(6)" ::: "memory");
  else if (VM == 4) asm volatile("s_waitcnt vmcnt(4)" ::: "memory");
  else asm volatile("s_waitcnt vmcnt(0)" ::: "memory");
  // step4: one barrier per tile (A(t+1) landed for ALL waves)
  barrier_raw();
  // step5: A fragment reads for tile t
  i32x4 af[8];
#pragma unroll
  for (int m = 0; m < 8; ++m)
    af[m] = *reinterpret_cast<const i32x4*>(buf + aRd + m * 1024);
  // step6: ph0
  asm volatile("s_waitcnt lgkmcnt(4)" ::: "memory");  // af[0..3] ready
  __builtin_amdgcn_sched_barrier(0);
  __builtin_amdgcn_s_setprio(1);
#pragma unroll
  for (int m = 0; m < 4; ++m)
#pragma unroll
    for (int n = 0; n < 4; ++n)
      acc[m][n] = __builtin_amdgcn_mfma_i32_16x16x64_i8(af[m], bfC[n],
                                                        acc[m][n], 0, 0, 0);
  __builtin_amdgcn_s_setprio(0);
  // ph1
  asm volatile("s_waitcnt lgkmcnt(0)" ::: "memory");  // af[4..7] ready
  __builtin_amdgcn_sched_barrier(0);
  __builtin_amdgcn_s_setprio(1);
#pragma unroll
  for (int m = 0; m < 4; ++m)
#pragma unroll
    for (int n = 0; n < 4; ++n)
      acc[4 + m][n] = __builtin_amdgcn_mfma_i32_16x16x64_i8(af[4 + m], bfC[n],
                                                            acc[4 + m][n], 0, 0, 0);
  __builtin_amdgcn_s_setprio(0);
}

__global__ __launch_bounds__(512, 2) void gemm_i8_kernel(
    const int8_t* __restrict__ A, const int8_t* __restrict__ B,
    float* __restrict__ C) {
  __shared__ __align__(16) int8_t lds[4 * 16384];  // 64 KiB, A only

  // XCD-aware bijective swizzle: nwg = 512 = 8 * 64
  int bid = blockIdx.x;
  int wg = (bid & 7) * 64 + (bid >> 3);
  int bm = wg >> 4;  // M/256 = 32
  int bn = wg & 15;  // N/256 = 16

  int tid = threadIdx.x;
  int wid = tid >> 6;
  int lane = tid & 63;
  int wr = wid >> 2;  // 0..1 (M)
  int wc = wid & 3;   // 0..3 (N)

  const int8_t* Asrc = A + (long)bm * 256 * K_DIM;
  const int8_t* Bsrc = B + (long)bn * 256 * K_DIM;

  // A staging (R2-proven layout): dst chunk = tid; row = tid>>2, c = tid&3;
  // src chunk = (tid&3) ^ ((row>>1)&3) = (tid&3) ^ ((tid>>3)&3)
  int srcChunk = ((tid & 3) ^ ((tid >> 3) & 3)) << 4;
  long sOff0 = (long)(tid >> 2) * K_DIM + srcChunk;  // rows 0..127
  long sOff1 = sOff0 + 128L * K_DIM;                 // rows 128..255
  int dstOff = wid * 1024;  // wave-uniform; HW adds lane*16

  // A frag reads (R2-proven, 0 conflicts): row = wr*128 + m*16 + (lane&15),
  // chunk = (lane>>4) ^ f(row), f = ((lane&15)>>1)&3
  int rswz = ((lane >> 4) ^ (((lane & 15) >> 1) & 3)) << 4;
  int aRd = (wr * 128 + (lane & 15)) * 64 + rswz;

  // B direct-global frag base: row = wc*64 + n*16 + (lane&15), k-chunk lane>>4
  long bOffG = (long)(wc * 64 + (lane & 15)) * K_DIM + ((lane >> 4) << 4);

  i32x4 bfA[4], bfB[4];
  i32x4 acc[8][4] = {};

  // prologue: B(0) regs + stage A(0), A(1)
#pragma unroll
  for (int n = 0; n < 4; ++n)
    bfA[n] = *reinterpret_cast<const i32x4*>(Bsrc + bOffG + (long)n * 16 * K_DIM);
#pragma unroll
  for (int t = 0; t < 2; ++t) {
    int8_t* buf = lds + t * 16384;
    long k0 = (long)t * 64;
    gload_lds16(Asrc + sOff0 + k0, buf + dstOff);
    gload_lds16(Asrc + sOff1 + k0, buf + 8192 + dstOff);
  }
  asm volatile("s_waitcnt vmcnt(2)" ::: "memory");  // B(0)+A(0) landed
  barrier_raw();

#pragma unroll 1
  for (int tt = 0; tt < 60; tt += 2) {
    tile_step<6, true, true>(tt, Asrc, Bsrc, sOff0, sOff1, bOffG, dstOff, lds,
                             aRd, bfA, bfB, acc);
    tile_step<6, true, true>(tt + 1, Asrc, Bsrc, sOff0, sOff1, bOffG, dstOff,
                             lds, aRd, bfB, bfA, acc);
  }
  tile_step<6, true, true>(60, Asrc, Bsrc, sOff0, sOff1, bOffG, dstOff, lds,
                           aRd, bfA, bfB, acc);
  tile_step<6, true, true>(61, Asrc, Bsrc, sOff0, sOff1, bOffG, dstOff, lds,
                           aRd, bfB, bfA, acc);
  tile_step<4, true, false>(62, Asrc, Bsrc, sOff0, sOff1, bOffG, dstOff, lds,
                            aRd, bfA, bfB, acc);
  tile_step<0, false, false>(63, Asrc, Bsrc, sOff0, sOff1, bOffG, dstOff, lds,
                             aRd, bfB, bfA, acc);

  // C/D 16x16 layout: col = lane&15, row = (lane>>4)*4 + reg
  long row0 = (long)bm * 256 + wr * 128 + ((lane >> 4) << 2);
  long col0 = (long)bn * 256 + wc * 64 + (lane & 15);
#pragma unroll
  for (int m = 0; m < 8; ++m)
#pragma unroll
    for (int n = 0; n < 4; ++n)
#pragma unroll
      for (int r = 0; r < 4; ++r)
        C[(row0 + m * 16 + r) * N_DIM + col0 + n * 16] = (float)acc[m][n][r];
}

extern "C" void kernel_launch(void* const* d_in, const int* in_sizes, int n_in,
                              void* d_out, int out_size, void* d_ws, size_t ws_size,
                              hipStream_t stream) {
  const float* x = (const float*)d_in[0];
  const float* w = (const float*)d_in[1];
  float* out = (float*)d_out;

  int8_t* xb = (int8_t*)d_ws;                // 32 MB: sign(x) [M][K]
  int8_t* wbt = xb + (size_t)M_DIM * K_DIM;  // 16 MB: sign(w)^T [N][K]

  pack_x_kernel<<<2048, 256, 0, stream>>>(x, xb, (long)M_DIM * K_DIM);
  pack_wt_kernel<<<dim3(N_DIM / 64, K_DIM / 64), 256, 0, stream>>>(w, wbt);
  gemm_i8_kernel<<<512, 512, 0, stream>>>(xb, wbt, out);
}